// Round 12
// baseline (225.119 us; speedup 1.0000x reference)
//
#include <hip/hip_runtime.h>

#define QLEN 1024
#define KLEN 2048   // MLEN + QLEN

static constexpr float INV2PI = 0.15915494309189535f;
static constexpr float TGUARD = 3e-5f;

// ---------------------------------------------------------------------------
// Fused projection + sincos precompute (verified rounds 2-11).
// Layout per token: float4 index = (tok*12 + part*4 + c)*32 + bh
//   part 0 = p, 1 = sin(R*p), 2 = cos(R*p);  c = d>>2;  elem = d&3
// ---------------------------------------------------------------------------
__global__ __launch_bounds__(256) void fa_proj_kernel(
    const float* __restrict__ h, const float* __restrict__ mems,
    const float* __restrict__ Wq, const float* __restrict__ Wk,
    const float* __restrict__ paramR,
    float* __restrict__ Rq3, float* __restrict__ Rk3)
{
    __shared__ float inT[128 * 36];
    const int tid  = threadIdx.x;
    const bool isQ = blockIdx.x < 128;
    const int  blk = isQ ? blockIdx.x : blockIdx.x - 128;
    const int row0 = blk * 32;
    const float* W   = isQ ? Wq : Wk;
    float*      out3 = isQ ? Rq3 : Rk3;

    for (int idx = tid; idx < 32 * 128; idx += 256) {
        int r = idx >> 7;
        int e = idx & 127;
        int grow = row0 + r;
        float v;
        if (isQ)               v = h[(size_t)grow * 128 + e];
        else if (grow < 4096)  v = mems[(size_t)grow * 128 + e];
        else                   v = h[(size_t)(grow - 4096) * 128 + e];
        inT[e * 36 + r] = v;
    }
    __syncthreads();

    const int col  = tid & 127;
    const int half = tid >> 7;

    float acc[16];
#pragma unroll
    for (int j = 0; j < 16; ++j) acc[j] = 0.0f;

#pragma unroll 2
    for (int e = 0; e < 128; ++e) {
        float w = W[e * 128 + col];
        const float4* ap = reinterpret_cast<const float4*>(&inT[e * 36 + half * 16]);
        float4 a0 = ap[0], a1 = ap[1], a2 = ap[2], a3 = ap[3];
        float av[16];
        av[0]=a0.x; av[1]=a0.y; av[2]=a0.z; av[3]=a0.w;
        av[4]=a1.x; av[5]=a1.y; av[6]=a1.z; av[7]=a1.w;
        av[8]=a2.x; av[9]=a2.y; av[10]=a2.z; av[11]=a2.w;
        av[12]=a3.x; av[13]=a3.y; av[14]=a3.z; av[15]=a3.w;
#pragma unroll
        for (int j = 0; j < 16; ++j) acc[j] = fmaf(av[j], w, acc[j]);
    }

    const int hh = col >> 4;
    const int d  = col & 15;
    const float Rrev = paramR[hh] * INV2PI;

#pragma unroll
    for (int j = 0; j < 16; ++j) {
        int r   = row0 + half * 16 + j;
        int tok = r >> 2;
        int b   = r & 3;
        int bh  = b * 8 + hh;
        float p = acc[j];
        float s = __builtin_amdgcn_sinf(Rrev * p);
        float c = __builtin_amdgcn_cosf(Rrev * p);
        int base = ((tok * 12 + (d >> 2)) * 32 + bh) * 4 + (d & 3);
        out3[base]        = p;
        out3[base + 512]  = s;
        out3[base + 1024] = c;
    }
}

// ---------------------------------------------------------------------------
// Main kernel — TQ=2 restructure.
// Diagnosis r6-r11: TQ=4's ~150-reg working set never fit the allocator's
// budget (VGPR_Count stuck at 76-84 < the 96-float q-state) -> off-file
// traffic (AGPR copies / re-reads) ~200 extra cyc per wave-token that no
// barrier/LDS/pin surgery removed. TQ=2 shrinks the working set to ~105
// regs so it genuinely fits in arch VGPRs at 4 waves/SIMD.
//   Block = 4 waves; wave owns 2 q-rows (qb = x*8 + wv*2).
//   Lane (dhalf = l>>5, bh = l&31) handles 8 of 16 d's for both q's.
//   Per token: 6 ds_read_b128 (k half-state), ~90 scalar VALU, 2 rcp,
//   1 shfl (half-product exchange), 1 nontemporal store (row qb+dhalf).
//   Grid 2048 = 128 q-blocks x 16 k-chunks (bid&15 -> XCD-pinned, 16=0 mod 8).
//   Counted barrier: 3 staging loads then 2 stores in the vmcnt queue ->
//   vmcnt(2) proves staging landed, stores stay in flight (r10-proven shape).
// ---------------------------------------------------------------------------
__global__ __launch_bounds__(256, 4) void fa_fourier_main(
    const float* __restrict__ Rq3, const float* __restrict__ Rk3,
    const float* __restrict__ paramR, float* __restrict__ out)
{
    __shared__ float4 kbuf[2][768];    // 2 x (2 tok x 12 x 32) float4 = 24576 B

    const int tid   = threadIdx.x;
    const int wv    = tid >> 6;
    const int l     = tid & 63;
    const int dhalf = l >> 5;          // which 8 of the 16 d's
    const int bh    = l & 31;
    const int bid   = blockIdx.x;
    const int ch    = bid & 15;        // k-chunk (128 tokens), XCD-pinned
    const int x     = bid >> 4;        // q-block 0..127
    const int k0    = ch * 128;
    const int qb    = x * 8 + wv * 2;

    const float R = paramR[bh & 7];

    // q-state: 2 q x {p,s,c} x own 8 d's = 48 scalar floats
    float qp[2][8], qs[2][8], qc[2][8];
    {
        const float4* qsrc = reinterpret_cast<const float4*>(Rq3);
#pragma unroll
        for (int q = 0; q < 2; ++q) {
            size_t tb = (size_t)(qb + q) * 12;
#pragma unroll
            for (int c2 = 0; c2 < 2; ++c2) {
                float4 pv = qsrc[(tb + 0 + dhalf * 2 + c2) * 32 + bh];
                float4 sv = qsrc[(tb + 4 + dhalf * 2 + c2) * 32 + bh];
                float4 cv = qsrc[(tb + 8 + dhalf * 2 + c2) * 32 + bh];
                qp[q][c2*4+0]=pv.x; qp[q][c2*4+1]=pv.y; qp[q][c2*4+2]=pv.z; qp[q][c2*4+3]=pv.w;
                qs[q][c2*4+0]=sv.x; qs[q][c2*4+1]=sv.y; qs[q][c2*4+2]=sv.z; qs[q][c2*4+3]=sv.w;
                qc[q][c2*4+0]=cv.x; qc[q][c2*4+1]=cv.y; qc[q][c2*4+2]=cv.z; qc[q][c2*4+3]=cv.w;
            }
        }
    }

    const float4* ksrc = reinterpret_cast<const float4*>(Rk3);

    // this lane stores q-row qb+dhalf
    float* outRow = out + ((size_t)(qb + dhalf) * KLEN + k0) * 32 + bh;

    // stage 2-token window w into buffer parity (3 x 16B per thread)
    auto stage = [&](int w, int parity) {
        size_t gbase = (size_t)(k0 + w * 2) * 384;
#pragma unroll
        for (int i = 0; i < 3; ++i) {
            int fi = i * 256 + tid;
            __builtin_amdgcn_global_load_lds(
                (const __attribute__((address_space(1))) void*)(ksrc + gbase + fi),
                (__attribute__((address_space(3))) void*)(&kbuf[parity][fi]),
                16, 0, 0);
        }
    };

    stage(0, 0);
    // prologue: drain staging (and q-state) loads, then barrier
    asm volatile("s_waitcnt vmcnt(0)\n\ts_barrier" ::: "memory");

    for (int w = 0; w < 64; ++w) {
        if (w < 63) stage(w + 1, (w + 1) & 1);
        const float4* kb = kbuf[w & 1];

#pragma unroll
        for (int t = 0; t < 2; ++t) {
            const float4* kst = kb + t * 384 + bh;
            float4 kpv0 = kst[(0 + dhalf * 2 + 0) * 32];
            float4 kpv1 = kst[(0 + dhalf * 2 + 1) * 32];
            float4 ksv0 = kst[(4 + dhalf * 2 + 0) * 32];
            float4 ksv1 = kst[(4 + dhalf * 2 + 1) * 32];
            float4 kcv0 = kst[(8 + dhalf * 2 + 0) * 32];
            float4 kcv1 = kst[(8 + dhalf * 2 + 1) * 32];
            const float kpe[8] = {kpv0.x,kpv0.y,kpv0.z,kpv0.w, kpv1.x,kpv1.y,kpv1.z,kpv1.w};
            const float kse[8] = {ksv0.x,ksv0.y,ksv0.z,ksv0.w, ksv1.x,ksv1.y,ksv1.z,ksv1.w};
            const float kce[8] = {kcv0.x,kcv0.y,kcv0.z,kcv0.w, kcv1.x,kcv1.y,kcv1.z,kcv1.w};

            float g[2];
#pragma unroll
            for (int q = 0; q < 2; ++q) {
                float u0 = qp[q][0] - kpe[0];
                float u1 = qp[q][1] - kpe[1];
                float u2 = qp[q][2] - kpe[2];
                float u3 = qp[q][3] - kpe[3];
                float u4 = qp[q][4] - kpe[4];
                float u5 = qp[q][5] - kpe[5];
                float u6 = qp[q][6] - kpe[6];
                float u7 = qp[q][7] - kpe[7];
                float n0 = fmaf(qs[q][0], kce[0], -(qc[q][0] * kse[0]));
                float n1 = fmaf(qs[q][1], kce[1], -(qc[q][1] * kse[1]));
                float n2 = fmaf(qs[q][2], kce[2], -(qc[q][2] * kse[2]));
                float n3 = fmaf(qs[q][3], kce[3], -(qc[q][3] * kse[3]));
                float n4 = fmaf(qs[q][4], kce[4], -(qc[q][4] * kse[4]));
                float n5 = fmaf(qs[q][5], kce[5], -(qc[q][5] * kse[5]));
                float n6 = fmaf(qs[q][6], kce[6], -(qc[q][6] * kse[6]));
                float n7 = fmaf(qs[q][7], kce[7], -(qc[q][7] * kse[7]));
                float uh = ((u0 * u1) * (u2 * u3)) * ((u4 * u5) * (u6 * u7));
                float nh = ((n0 * n1) * (n2 * n3)) * ((n4 * n5) * (n6 * n7));
                // v_min3-fusable guard tree (abs folds as src modifier)
                float ma = fminf(fminf(fabsf(u0), fabsf(u1)), fabsf(u2));
                float mb = fminf(fminf(fabsf(u3), fabsf(u4)), fabsf(u5));
                float mc = fminf(fminf(fabsf(u6), fabsf(u7)), ma);
                float mn = fminf(mb, mc);
                if (__builtin_expect(mn < TGUARD, 0)) {
                    // lane-local guarded recompute of own half (rare)
                    float pu = 1.0f, pn = 1.0f;
#pragma unroll
                    for (int e = 0; e < 8; ++e) {
                        float u = qp[q][e] - kpe[e];
                        float n = fmaf(qs[q][e], kce[e], -(qc[q][e] * kse[e]));
                        if (fabsf(u) < TGUARD) {
                            float ru = R * u;
                            n = R * fmaf(-ru * ru, 0.16666667f, 1.0f);
                            u = 1.0f;
                        }
                        pu *= u; pn *= n;
                    }
                    if (fabsf(pu) < 1e-30f) pu = (pu < 0.0f) ? -1e-30f : 1e-30f;
                    uh = pu; nh = pn;
                }
                g[q] = nh * __builtin_amdgcn_rcpf(uh);
            }

            // pair exchange: dhalf0 sends g[1] (partner stores q1), gets
            // partner's g[0]; dhalf1 sends g[0], gets partner's g[1].
            float send = dhalf ? g[0] : g[1];
            float recv = __shfl_xor(send, 32, 64);
            float mine = dhalf ? g[1] : g[0];

            __builtin_nontemporal_store(fabsf(mine * recv),
                                        outRow + (size_t)(w * 2 + t) * 32);
        }

        if (w < 63) {
            // counted-vmcnt barrier (T4): per window the vmcnt queue is
            // [3 staging loads][2 stores] -> vmcnt(2) proves the loads
            // landed in LDS; the 2 stores stay in flight across it.
            asm volatile("s_waitcnt vmcnt(2)\n\ts_barrier" ::: "memory");
        }
    }
}

extern "C" void kernel_launch(void* const* d_in, const int* in_sizes, int n_in,
                              void* d_out, int out_size, void* d_ws, size_t ws_size,
                              hipStream_t stream)
{
    const float* h    = (const float*)d_in[0];   // [1024,4,128]
    const float* mems = (const float*)d_in[1];   // [1024,4,128]
    const float* Wq   = (const float*)d_in[2];   // [128,128]
    const float* Wk   = (const float*)d_in[3];   // [128,128]
    const float* R    = (const float*)d_in[4];   // [8]
    float* out = (float*)d_out;                  // [1024,2048,4,8] fp32

    float* Rq3 = (float*)d_ws;                   // 1024*1536 floats (6 MB)
    float* Rk3 = Rq3 + (size_t)1024 * 1536;      // 2048*1536 floats (12 MB)

    fa_proj_kernel<<<dim3(384), 256, 0, stream>>>(h, mems, Wq, Wk, R, Rq3, Rk3);

    // 128 q-blocks x 16 k-chunks = 2048 blocks; bid&15 = chunk (XCD-clean)
    fa_fourier_main<<<dim3(2048), 256, 0, stream>>>(Rq3, Rk3, R, out);
}

// Round 13
// 207.827 us; speedup vs baseline: 1.0832x; 1.0832x over previous
//
#include <hip/hip_runtime.h>

#define QLEN 1024
#define KLEN 2048   // MLEN + QLEN

typedef float f32x4 __attribute__((ext_vector_type(4)));

static constexpr float INV2PI = 0.15915494309189535f;
static constexpr float TGUARD = 3e-5f;

// ---------------------------------------------------------------------------
// Fused projection + sincos precompute (verified rounds 2-12).
// Layout per token: float4 index = (tok*12 + part*4 + c)*32 + bh
//   part 0 = p, 1 = sin(R*p), 2 = cos(R*p);  c = d>>2;  elem = d&3
// ---------------------------------------------------------------------------
__global__ __launch_bounds__(256) void fa_proj_kernel(
    const float* __restrict__ h, const float* __restrict__ mems,
    const float* __restrict__ Wq, const float* __restrict__ Wk,
    const float* __restrict__ paramR,
    float* __restrict__ Rq3, float* __restrict__ Rk3)
{
    __shared__ float inT[128 * 36];
    const int tid  = threadIdx.x;
    const bool isQ = blockIdx.x < 128;
    const int  blk = isQ ? blockIdx.x : blockIdx.x - 128;
    const int row0 = blk * 32;
    const float* W   = isQ ? Wq : Wk;
    float*      out3 = isQ ? Rq3 : Rk3;

    for (int idx = tid; idx < 32 * 128; idx += 256) {
        int r = idx >> 7;
        int e = idx & 127;
        int grow = row0 + r;
        float v;
        if (isQ)               v = h[(size_t)grow * 128 + e];
        else if (grow < 4096)  v = mems[(size_t)grow * 128 + e];
        else                   v = h[(size_t)(grow - 4096) * 128 + e];
        inT[e * 36 + r] = v;
    }
    __syncthreads();

    const int col  = tid & 127;
    const int half = tid >> 7;

    float acc[16];
#pragma unroll
    for (int j = 0; j < 16; ++j) acc[j] = 0.0f;

#pragma unroll 2
    for (int e = 0; e < 128; ++e) {
        float w = W[e * 128 + col];
        const float4* ap = reinterpret_cast<const float4*>(&inT[e * 36 + half * 16]);
        float4 a0 = ap[0], a1 = ap[1], a2 = ap[2], a3 = ap[3];
        float av[16];
        av[0]=a0.x; av[1]=a0.y; av[2]=a0.z; av[3]=a0.w;
        av[4]=a1.x; av[5]=a1.y; av[6]=a1.z; av[7]=a1.w;
        av[8]=a2.x; av[9]=a2.y; av[10]=a2.z; av[11]=a2.w;
        av[12]=a3.x; av[13]=a3.y; av[14]=a3.z; av[15]=a3.w;
#pragma unroll
        for (int j = 0; j < 16; ++j) acc[j] = fmaf(av[j], w, acc[j]);
    }

    const int hh = col >> 4;
    const int d  = col & 15;
    const float Rrev = paramR[hh] * INV2PI;

#pragma unroll
    for (int j = 0; j < 16; ++j) {
        int r   = row0 + half * 16 + j;
        int tok = r >> 2;
        int b   = r & 3;
        int bh  = b * 8 + hh;
        float p = acc[j];
        float s = __builtin_amdgcn_sinf(Rrev * p);
        float c = __builtin_amdgcn_cosf(Rrev * p);
        int base = ((tok * 12 + (d >> 2)) * 32 + bh) * 4 + (d & 3);
        out3[base]        = p;
        out3[base + 512]  = s;
        out3[base + 1024] = c;
    }
}

// ---------------------------------------------------------------------------
// Main kernel — TQ=4, resident-q-state version.
// Diagnosis r6-r12: busy = Ntok*(F + TQ*C), C=110cy/q (the math), F=188cy
// fixed per token. F was inflated by (a) "memory"-clobber barriers each
// window -> allocator remats q-state loads inside the loop (VGPR_Count
// 56-84 < q-state size for 7 rounds), (b) scalar-array rebuilds of k-state.
// This round: bare s_barrier asm (NO memory clobber) fenced by
// sched_barrier(0) for LDS-read ordering (rule-18); q-state as ext-vector
// values pinned by opaque asm (RA cannot remat asm results);
// launch_bounds(256,3) so the ~154-reg live set fits the 170 budget;
// direct vector-component math, no scalar arrays.
//   Block = 4 waves; wave owns 4 q-rows (qb = x*16 + wv*4).
//   Lane (dhalf = l>>5, bh = l&31) handles 8 of 16 d's for all 4 q's.
//   2-token LDS windows (24576 B, dbuf, global_load_lds).
//   Counted barrier: queue/window = [3 loads][4 stores] -> vmcnt(4).
// ---------------------------------------------------------------------------
__global__ __launch_bounds__(256, 3) void fa_fourier_main(
    const float* __restrict__ Rq3, const float* __restrict__ Rk3,
    const float* __restrict__ paramR, float* __restrict__ out)
{
    __shared__ f32x4 kbuf[2][768];    // 2 x (2 tok x 12 x 32) float4 = 24576 B

    const int tid   = threadIdx.x;
    const int wv    = tid >> 6;
    const int l     = tid & 63;
    const int dhalf = l >> 5;          // which 8 of the 16 d's
    const int bh    = l & 31;
    const int bid   = blockIdx.x;
    const int ch    = bid & 15;        // k-chunk (128 tokens), XCD-pinned
    const int x     = bid >> 4;        // q-block 0..63
    const int k0    = ch * 128;
    const int qb    = x * 16 + wv * 4;

    const float R = paramR[bh & 7];

    // q-state: 4 q x {p,s,c} x 2 f32x4 (own 8 d's) = 96 floats, PINNED.
    f32x4 qp[4][2], qs[4][2], qc[4][2];
    {
        const f32x4* qsrc = reinterpret_cast<const f32x4*>(Rq3);
#pragma unroll
        for (int q = 0; q < 4; ++q) {
            size_t tb = (size_t)(qb + q) * 12;
#pragma unroll
            for (int j = 0; j < 2; ++j) {
                qp[q][j] = qsrc[(tb + 0 + dhalf * 2 + j) * 32 + bh];
                qs[q][j] = qsrc[(tb + 4 + dhalf * 2 + j) * 32 + bh];
                qc[q][j] = qsrc[(tb + 8 + dhalf * 2 + j) * 32 + bh];
            }
        }
    }
    // Opaque pin: RA cannot rematerialize asm results -> q-state must stay
    // live in registers for the whole kernel.
#pragma unroll
    for (int q = 0; q < 4; ++q)
#pragma unroll
        for (int j = 0; j < 2; ++j)
            asm volatile("" : "+v"(qp[q][j]), "+v"(qs[q][j]), "+v"(qc[q][j]));

    const f32x4* ksrc = reinterpret_cast<const f32x4*>(Rk3);

    // this lane stores q rows {qb+dhalf*2, qb+dhalf*2+1}
    float* outA = out + ((size_t)(qb + dhalf * 2) * KLEN + k0) * 32 + bh;
    float* outB = outA + (size_t)KLEN * 32;

    // stage 2-token window w into buffer parity (3 x 16B per thread)
    auto stage = [&](int w, int parity) {
        size_t gbase = (size_t)(k0 + w * 2) * 384;
#pragma unroll
        for (int i = 0; i < 3; ++i) {
            int fi = i * 256 + tid;
            __builtin_amdgcn_global_load_lds(
                (const __attribute__((address_space(1))) void*)(ksrc + gbase + fi),
                (__attribute__((address_space(3))) void*)(&kbuf[parity][fi]),
                16, 0, 0);
        }
    };

    stage(0, 0);
    __builtin_amdgcn_sched_barrier(0);
    asm volatile("s_waitcnt vmcnt(0)\n\ts_barrier");
    __builtin_amdgcn_sched_barrier(0);

    for (int w = 0; w < 64; ++w) {
        if (w < 63) stage(w + 1, (w + 1) & 1);
        const f32x4* kb = kbuf[w & 1] + bh;

#pragma unroll
        for (int t = 0; t < 2; ++t) {
            // k half-state: 6 f32x4, offsets are compile-time multiples of 512B
            f32x4 kp0 = kb[(t * 12 + 0 + dhalf * 2 + 0) * 32];
            f32x4 kp1 = kb[(t * 12 + 0 + dhalf * 2 + 1) * 32];
            f32x4 ks0 = kb[(t * 12 + 4 + dhalf * 2 + 0) * 32];
            f32x4 ks1 = kb[(t * 12 + 4 + dhalf * 2 + 1) * 32];
            f32x4 kc0 = kb[(t * 12 + 8 + dhalf * 2 + 0) * 32];
            f32x4 kc1 = kb[(t * 12 + 8 + dhalf * 2 + 1) * 32];

            float g[4];
#pragma unroll
            for (int q = 0; q < 4; ++q) {
                float u0 = qp[q][0][0] - kp0[0];
                float u1 = qp[q][0][1] - kp0[1];
                float u2 = qp[q][0][2] - kp0[2];
                float u3 = qp[q][0][3] - kp0[3];
                float u4 = qp[q][1][0] - kp1[0];
                float u5 = qp[q][1][1] - kp1[1];
                float u6 = qp[q][1][2] - kp1[2];
                float u7 = qp[q][1][3] - kp1[3];
                float n0 = fmaf(qs[q][0][0], kc0[0], -(qc[q][0][0] * ks0[0]));
                float n1 = fmaf(qs[q][0][1], kc0[1], -(qc[q][0][1] * ks0[1]));
                float n2 = fmaf(qs[q][0][2], kc0[2], -(qc[q][0][2] * ks0[2]));
                float n3 = fmaf(qs[q][0][3], kc0[3], -(qc[q][0][3] * ks0[3]));
                float n4 = fmaf(qs[q][1][0], kc1[0], -(qc[q][1][0] * ks1[0]));
                float n5 = fmaf(qs[q][1][1], kc1[1], -(qc[q][1][1] * ks1[1]));
                float n6 = fmaf(qs[q][1][2], kc1[2], -(qc[q][1][2] * ks1[2]));
                float n7 = fmaf(qs[q][1][3], kc1[3], -(qc[q][1][3] * ks1[3]));
                float uh = ((u0 * u1) * (u2 * u3)) * ((u4 * u5) * (u6 * u7));
                float nh = ((n0 * n1) * (n2 * n3)) * ((n4 * n5) * (n6 * n7));
                // v_min3-fusable guard tree (abs folds as src modifier)
                float ma = fminf(fminf(fabsf(u0), fabsf(u1)), fabsf(u2));
                float mb = fminf(fminf(fabsf(u3), fabsf(u4)), fabsf(u5));
                float mc = fminf(fminf(fabsf(u6), fabsf(u7)), ma);
                float mn = fminf(mb, mc);
                if (__builtin_expect(mn < TGUARD, 0)) {
                    // lane-local guarded recompute of own half (rare)
                    float pu = 1.0f, pn = 1.0f;
#pragma unroll
                    for (int j = 0; j < 2; ++j) {
#pragma unroll
                        for (int e = 0; e < 4; ++e) {
                            float kpj = (j ? kp1 : kp0)[e];
                            float ksj = (j ? ks1 : ks0)[e];
                            float kcj = (j ? kc1 : kc0)[e];
                            float u = qp[q][j][e] - kpj;
                            float n = fmaf(qs[q][j][e], kcj, -(qc[q][j][e] * ksj));
                            if (fabsf(u) < TGUARD) {
                                float ru = R * u;
                                n = R * fmaf(-ru * ru, 0.16666667f, 1.0f);
                                u = 1.0f;
                            }
                            pu *= u; pn *= n;
                        }
                    }
                    if (fabsf(pu) < 1e-30f) pu = (pu < 0.0f) ? -1e-30f : 1e-30f;
                    uh = pu; nh = pn;
                }
                g[q] = nh * __builtin_amdgcn_rcpf(uh);
            }

            // pair exchange: send the half the partner stores, pull ours
            float sendA = dhalf ? g[0] : g[2];
            float sendB = dhalf ? g[1] : g[3];
            float recvA = __shfl_xor(sendA, 32, 64);
            float recvB = __shfl_xor(sendB, 32, 64);
            float myA   = dhalf ? g[2] : g[0];
            float myB   = dhalf ? g[3] : g[1];

            const int t32 = (w * 2 + t) * 32;
            __builtin_nontemporal_store(fabsf(myA * recvA), outA + t32);
            __builtin_nontemporal_store(fabsf(myB * recvB), outB + t32);
        }

        if (w < 63) {
            // counted-vmcnt barrier: queue = [3 loads][4 stores] -> vmcnt(4)
            // proves next window's staging landed; stores stay in flight.
            // sched_barrier(0) fences (rule-18): no LDS read may cross.
            __builtin_amdgcn_sched_barrier(0);
            asm volatile("s_waitcnt vmcnt(4)\n\ts_barrier");
            __builtin_amdgcn_sched_barrier(0);
        }
    }
}

extern "C" void kernel_launch(void* const* d_in, const int* in_sizes, int n_in,
                              void* d_out, int out_size, void* d_ws, size_t ws_size,
                              hipStream_t stream)
{
    const float* h    = (const float*)d_in[0];   // [1024,4,128]
    const float* mems = (const float*)d_in[1];   // [1024,4,128]
    const float* Wq   = (const float*)d_in[2];   // [128,128]
    const float* Wk   = (const float*)d_in[3];   // [128,128]
    const float* R    = (const float*)d_in[4];   // [8]
    float* out = (float*)d_out;                  // [1024,2048,4,8] fp32

    float* Rq3 = (float*)d_ws;                   // 1024*1536 floats (6 MB)
    float* Rk3 = Rq3 + (size_t)1024 * 1536;      // 2048*1536 floats (12 MB)

    fa_proj_kernel<<<dim3(384), 256, 0, stream>>>(h, mems, Wq, Wk, R, Rq3, Rk3);

    // 64 q-blocks x 16 k-chunks = 1024 blocks; bid&15 = chunk (XCD-clean)
    fa_fourier_main<<<dim3(1024), 256, 0, stream>>>(Rq3, Rk3, R, out);
}